// Round 8
// baseline (182.819 us; speedup 1.0000x reference)
//
#include <hip/hip_runtime.h>
#include <cstdint>
#include <cstddef>

typedef __bf16 bf16x8 __attribute__((ext_vector_type(8)));
typedef __bf16 bf16x2v __attribute__((ext_vector_type(2)));
typedef unsigned short u16;
typedef u16 u16x8v __attribute__((ext_vector_type(8)));
typedef float  f32x4  __attribute__((ext_vector_type(4)));
typedef unsigned int u32;

#define MFMA16(a, b, c) __builtin_amdgcn_mfma_f32_16x16x32_bf16((a), (b), (c), 0, 0, 0)
#define ASYNC16(g, l)                                                              \
  __builtin_amdgcn_global_load_lds(                                                \
      (const __attribute__((address_space(1))) unsigned int*)(g),                  \
      (__attribute__((address_space(3))) unsigned int*)(l), 16, 0, 0)

__device__ __forceinline__ u16 f2bf(float f) {
  unsigned u = __builtin_bit_cast(unsigned, f);
  u += 0x7fffu + ((u >> 16) & 1u);
  return (u16)(u >> 16);
}

// packed fp32x2 -> bf16x2 (RNE) via hardware cvt
__device__ __forceinline__ u32 cvt2(float a, float b) {
  bf16x2v t;
  t[0] = (__bf16)a;
  t[1] = (__bf16)b;
  return __builtin_bit_cast(u32, t);
}

#define SEQ 2048
#define CH  1024
#define NH  16
#define HD  64
// log2(e) / sqrt(64) folded into stored Q so softmax uses exp2
#define QSCALE 0.18033688011112042f

// ------------- fused prep: cast x + transpose-cast qkv_w + proj_w -------------
// (round-2 original, measured-best; prep-v2 variant was +1.1us — reverted)
__global__ void __launch_bounds__(256) prep_kernel(const float* __restrict__ x,
                                                   const float* __restrict__ qkv_w,
                                                   const float* __restrict__ proj_w,
                                                   u16* __restrict__ xb,
                                                   u16* __restrict__ wqkvt,
                                                   u16* __restrict__ wprojt) {
  __shared__ u16 t[64][68];
  int bx = blockIdx.x;
  int tx = threadIdx.x;
  if (bx < 4096) {
    int i = bx * 256 + tx;
    float4 v = ((const float4*)x)[i];
    ushort4 o;
    o.x = f2bf(v.x); o.y = f2bf(v.y); o.z = f2bf(v.z); o.w = f2bf(v.w);
    ((ushort4*)xb)[i] = o;
    return;
  }
  const float* in; u16* out; int R, C, c0, r0;
  if (bx < 4096 + 768) {
    int i = bx - 4096;
    in = qkv_w; out = wqkvt; R = 1024; C = 3072;
    c0 = (i % 48) * 64; r0 = (i / 48) * 64;
  } else {
    int i = bx - 4864;
    in = proj_w; out = wprojt; R = 1024; C = 1024;
    c0 = (i % 16) * 64; r0 = (i / 16) * 64;
  }
  int rr = tx >> 6, cc = tx & 63;
#pragma unroll
  for (int i = 0; i < 16; ++i) {
    int r = i * 4 + rr;
    t[r][cc] = f2bf(in[(size_t)(r0 + r) * C + c0 + cc]);
  }
  __syncthreads();
#pragma unroll
  for (int i = 0; i < 16; ++i) {
    int r = i * 4 + rr;
    out[(size_t)(c0 + r) * R + r0 + cc] = t[cc][r];
  }
}

// ------------- GEMM v4 (round-2, measured-best) — used for gemm2 (mode 1) -------
template <int MT>
__global__ void __launch_bounds__(256) gemm_kernel(const u16* __restrict__ A,
                                                   const u16* __restrict__ Bt,
                                                   const float* __restrict__ bias,
                                                   u16* __restrict__ qk,
                                                   u16* __restrict__ vtout,
                                                   float* __restrict__ outf,
                                                   int K, int mode) {
  constexpr int R = MT * 32;
  __shared__ alignas(16) u16 smem[2 * R * 64 + 2 * 128 * 64];
  auto As = (u16(*)[R * 64])smem;
  auto Bs = (u16(*)[128 * 64])(smem + 2 * R * 64);
  int tid = threadIdx.x;
  int lane = tid & 63, wave = tid >> 6;
  int wm = wave >> 1, wn = wave & 1;
  int qr = lane & 15, quad = lane >> 4;
  size_t rowA = (size_t)blockIdx.y * R;
  size_t rowB = (size_t)blockIdx.x * 128;

  int klr = lane >> 3;
  int kcs = (lane & 7) ^ klr;

  f32x4 acc[MT][4];
#pragma unroll
  for (int mt = 0; mt < MT; ++mt)
#pragma unroll
    for (int nt = 0; nt < 4; ++nt) acc[mt][nt] = (f32x4){0.f, 0.f, 0.f, 0.f};

  auto stage = [&](int buf, int k0) {
#pragma unroll
    for (int i = 0; i < R / 32; ++i) {
      int ar = wave * (R / 4) + i * 8;
      ASYNC16(A + (rowA + ar + klr) * K + k0 + kcs * 8, &As[buf][ar * 64 + lane * 8]);
    }
#pragma unroll
    for (int i = 0; i < 4; ++i) {
      int br = wave * 32 + i * 8;
      ASYNC16(Bt + (rowB + br + klr) * K + k0 + kcs * 8, &Bs[buf][br * 64 + lane * 8]);
    }
  };

  stage(0, 0);
  int iters = K >> 6;
  for (int t = 0; t < iters; ++t) {
    int cur = t & 1;
    __syncthreads();
    if (t + 1 < iters) stage(cur ^ 1, (t + 1) * 64);
#pragma unroll
    for (int ks = 0; ks < 2; ++ks) {
      bf16x8 af[MT], bfr[4];
#pragma unroll
      for (int mt = 0; mt < MT; ++mt) {
        int row = wm * (MT * 16) + mt * 16 + qr;
        af[mt] = *(const bf16x8*)&As[cur][row * 64 + (((ks * 4 + quad) ^ (qr & 7)) << 3)];
      }
#pragma unroll
      for (int nt = 0; nt < 4; ++nt) {
        int row = wn * 64 + nt * 16 + qr;
        bfr[nt] = *(const bf16x8*)&Bs[cur][row * 64 + (((ks * 4 + quad) ^ (qr & 7)) << 3)];
      }
#pragma unroll
      for (int mt = 0; mt < MT; ++mt)
#pragma unroll
        for (int nt = 0; nt < 4; ++nt)
          acc[mt][nt] = MFMA16(af[mt], bfr[nt], acc[mt][nt]);
    }
    __syncthreads();
  }

  __syncthreads();

  if (mode == 1) {
    float* epf = (float*)smem;
#pragma unroll
    for (int nt = 0; nt < 4; ++nt) {
      int cl = wn * 64 + nt * 16 + qr;
      float bv = bias[rowB + cl];
#pragma unroll
      for (int mt = 0; mt < MT; ++mt) {
        int rl = wm * (MT * 16) + mt * 16 + quad * 4;
#pragma unroll
        for (int r = 0; r < 4; ++r)
          epf[(rl + r) * 132 + cl] = acc[mt][nt][r] + bv;
      }
    }
    __syncthreads();
    int rr = wave * 2 + (lane >> 5);
    int cc = (lane & 31) * 4;
#pragma unroll
    for (int p = 0; p < R / 8; ++p) {
      int row = p * 8 + rr;
      float4 v = *(const float4*)&epf[row * 132 + cc];
      *(float4*)&outf[(rowA + row) * 1024 + rowB + cc] = v;
    }
  } else if ((int)rowB < 2048) {
    float sc = ((int)rowB < 1024) ? QSCALE : 1.0f;
    u16* ep = smem;
#pragma unroll
    for (int nt = 0; nt < 4; ++nt) {
      int cl = wn * 64 + nt * 16 + qr;
      float bv = bias[rowB + cl];
#pragma unroll
      for (int mt = 0; mt < MT; ++mt) {
        int rl = wm * (MT * 16) + mt * 16 + quad * 4;
#pragma unroll
        for (int r = 0; r < 4; ++r)
          ep[(rl + r) * 136 + cl] = f2bf((acc[mt][nt][r] + bv) * sc);
      }
    }
    __syncthreads();
    int rr = wave * 4 + (lane >> 4);
    int cc = (lane & 15) * 8;
#pragma unroll
    for (int p = 0; p < R / 16; ++p) {
      int row = p * 16 + rr;
      u16x8v v = *(const u16x8v*)&ep[row * 136 + cc];
      *(u16x8v*)&qk[(rowA + row) * 2048 + rowB + cc] = v;
    }
  } else {
    u16* ep = smem;
#pragma unroll
    for (int nt = 0; nt < 4; ++nt) {
      int cl = wn * 64 + nt * 16 + qr;
      float bv = bias[rowB + cl];
#pragma unroll
      for (int mt = 0; mt < MT; ++mt) {
        int rl = wm * (MT * 16) + mt * 16 + quad * 4;
        ushort4 pv;
        pv.x = f2bf(acc[mt][nt][0] + bv);
        pv.y = f2bf(acc[mt][nt][1] + bv);
        pv.z = f2bf(acc[mt][nt][2] + bv);
        pv.w = f2bf(acc[mt][nt][3] + bv);
        *(ushort4*)&ep[cl * 136 + rl] = pv;
      }
    }
    __syncthreads();
    int batch = (int)(rowA >> 11);
    int n_base = (int)(rowA & 2047);
    int rr = wave * 4 + (lane >> 4);
    int cc = (lane & 15) * 8;
#pragma unroll
    for (int p = 0; p < 8; ++p) {
      int d = p * 16 + rr;
      int cglob = (int)rowB - 2048 + d;
      int bh_ = batch * 16 + (cglob >> 6);
      u16x8v v = *(const u16x8v*)&ep[d * 136 + cc];
      *(u16x8v*)&vtout[(size_t)bh_ * 131072 + (size_t)(cglob & 63) * 2048 + n_base + cc] = v;
    }
  }
}

// ------------- GEMM-256: 256x256 tile, 8 waves, 8-phase schedule (T3+T4+T5) ----
// For gemm1 (qkv) only. LDS 128KB = 2buf x {A-half[128][64], ...}x2 x {A,B}.
// Same [128][64] layout + 8-chunk XOR swizzle as the proven v4 kernel.
// Per iter (2 K-tiles): 8 phases x {raw s_barrier; stage?; ds_reads; 16 MFMA}.
// Stages issued at ph1 (tile 2j+1 -> buf1) and ph5 (tile 2j+2 -> buf0), each
// drained by vmcnt(0) THREE phases later, placed BEFORE the barrier so all
// waves' DMA is visible after it (cross-wave rule). No full drains per K-tile.
// s_setprio(1) wraps each 16-MFMA cluster (T5; pays on phase-split schedules).
#define G256_LDSA(buf, ks)                                                         \
  {                                                                                \
    const u16* base_ = &smem[(buf) * 2 * 8192 + wm * 8192];                        \
    _Pragma("unroll") for (int mt = 0; mt < 8; ++mt)                               \
        afr[mt] = *(const bf16x8*)&base_[(mt * 16 + qr) * 64 +                     \
                                         ((((ks) * 4 + quad) ^ (qr & 7)) << 3)];   \
  }
#define G256_LDSB(buf, ks, np)                                                     \
  {                                                                                \
    const u16* base_ = &smem[32768 + (buf) * 2 * 8192 + (wn >> 1) * 8192];         \
    _Pragma("unroll") for (int u = 0; u < 2; ++u)                                  \
        bfr[u] = *(const bf16x8*)&base_[((wn & 1) * 64 + ((np) * 2 + u) * 16 + qr) * 64 + \
                                        ((((ks) * 4 + quad) ^ (qr & 7)) << 3)];    \
  }
#define G256_MMA(np)                                                               \
  {                                                                                \
    __builtin_amdgcn_s_setprio(1);                                                 \
    _Pragma("unroll") for (int mt = 0; mt < 8; ++mt) {                             \
      acc[mt][(np) * 2] = MFMA16(afr[mt], bfr[0], acc[mt][(np) * 2]);              \
      acc[mt][(np) * 2 + 1] = MFMA16(afr[mt], bfr[1], acc[mt][(np) * 2 + 1]);      \
    }                                                                              \
    __builtin_amdgcn_s_setprio(0);                                                 \
  }
#define G256_STAGE_A(buf, t)                                                       \
  _Pragma("unroll") for (int h = 0; h < 2; ++h)                                    \
  _Pragma("unroll") for (int i = 0; i < 2; ++i) {                                  \
    int rl = i * 64 + wave * 8;                                                    \
    ASYNC16(A + (rowA + h * 128 + rl + klr) * 1024 + (t) * 64 + kcs * 8,           \
            &smem[(buf) * 2 * 8192 + h * 8192 + rl * 64 + lane * 8]);              \
  }
#define G256_STAGE_B(buf, t)                                                       \
  _Pragma("unroll") for (int h = 0; h < 2; ++h)                                    \
  _Pragma("unroll") for (int i = 0; i < 2; ++i) {                                  \
    int rl = i * 64 + wave * 8;                                                    \
    ASYNC16(Bt + (rowB + h * 128 + rl + klr) * 1024 + (t) * 64 + kcs * 8,          \
            &smem[32768 + (buf) * 2 * 8192 + h * 8192 + rl * 64 + lane * 8]);      \
  }
#define G256_BAR() __builtin_amdgcn_s_barrier()
#define G256_VM0() asm volatile("s_waitcnt vmcnt(0)" ::: "memory")

__global__ void __launch_bounds__(512) gemm256_kernel(const u16* __restrict__ A,
                                                      const u16* __restrict__ Bt,
                                                      const float* __restrict__ bias,
                                                      u16* __restrict__ qk,
                                                      u16* __restrict__ vtout) {
  __shared__ alignas(16) u16 smem[65536];  // 128KB
  int tid = threadIdx.x;
  int lane = tid & 63, wave = tid >> 6;
  int wm = wave >> 2, wn = wave & 3;       // 2M x 4N waves; per-wave out 128x64
  int qr = lane & 15, quad = lane >> 4;
  int klr = lane >> 3;
  int kcs = (lane & 7) ^ klr;

  size_t rowA = (size_t)blockIdx.y * 256;
  size_t rowB = (size_t)blockIdx.x * 256;

  f32x4 acc[8][4];
#pragma unroll
  for (int mt = 0; mt < 8; ++mt)
#pragma unroll
    for (int nt = 0; nt < 4; ++nt) acc[mt][nt] = (f32x4){0.f, 0.f, 0.f, 0.f};

  bf16x8 afr[8], bfr[2];

  // prologue: tile 0 -> buf0, drain own loads, then loop (barrier publishes)
  G256_STAGE_A(0, 0);
  G256_STAGE_B(0, 0);
  G256_VM0();

  for (int j = 0; j < 8; ++j) {
    // ph1: buf0/ks0/np01 ; stage tile 2j+1 -> buf1 (buf1 died at prev ph8)
    G256_BAR();
    G256_STAGE_A(1, 2 * j + 1);
    G256_STAGE_B(1, 2 * j + 1);
    G256_LDSA(0, 0);
    G256_LDSB(0, 0, 0);
    G256_MMA(0);
    // ph2: buf0/ks0/np23 (afr reused)
    G256_BAR();
    G256_LDSB(0, 0, 1);
    G256_MMA(1);
    // ph3: buf0/ks1/np01
    G256_BAR();
    G256_LDSA(0, 1);
    G256_LDSB(0, 1, 0);
    G256_MMA(0);
    // ph4: buf0/ks1/np23 ; drain own ph1 stages BEFORE the ph5 barrier
    G256_BAR();
    G256_LDSB(0, 1, 1);
    G256_MMA(1);
    G256_VM0();
    // ph5: buf1/ks0/np01 ; stage tile 2j+2 -> buf0 (buf0 died at ph4)
    G256_BAR();
    if (j + 1 < 8) {
      G256_STAGE_A(0, 2 * j + 2);
      G256_STAGE_B(0, 2 * j + 2);
    }
    G256_LDSA(1, 0);
    G256_LDSB(1, 0, 0);
    G256_MMA(0);
    // ph6
    G256_BAR();
    G256_LDSB(1, 0, 1);
    G256_MMA(1);
    // ph7
    G256_BAR();
    G256_LDSA(1, 1);
    G256_LDSB(1, 1, 0);
    G256_MMA(0);
    // ph8 ; drain own ph5 stages before next iter's ph1 barrier
    G256_BAR();
    G256_LDSB(1, 1, 1);
    G256_MMA(1);
    G256_VM0();
  }
  __syncthreads();  // full fence before LDS reuse in epilogue

  // ---- epilogue: LDS restage -> coalesced 16B stores (validated recipe) ----
  int bx = blockIdx.x;
  float bv[4];
#pragma unroll
  for (int nt = 0; nt < 4; ++nt) bv[nt] = bias[rowB + wn * 64 + nt * 16 + qr];

  u16* ep = smem;
  if (bx < 8) {
    // Q (scaled) / K -> qk buffer, stride 2048; two 128-row chunks [128][264]
    float sc = (bx < 4) ? QSCALE : 1.0f;
#pragma unroll
    for (int cm = 0; cm < 2; ++cm) {
      if (wm == cm) {
#pragma unroll
        for (int mt = 0; mt < 8; ++mt)
#pragma unroll
          for (int nt = 0; nt < 4; ++nt) {
            int rl = mt * 16 + quad * 4;
            int cl = wn * 64 + nt * 16 + qr;
#pragma unroll
            for (int r = 0; r < 4; ++r)
              ep[(rl + r) * 264 + cl] = f2bf((acc[mt][nt][r] + bv[nt]) * sc);
          }
      }
      __syncthreads();
      int row = tid >> 5;
      int c0 = (tid & 31) * 8;
#pragma unroll
      for (int p = 0; p < 8; ++p) {
        int rr = p * 16 + row;
        u16x8v v = *(const u16x8v*)&ep[rr * 264 + c0];
        *(u16x8v*)&qk[(rowA + cm * 128 + rr) * 2048 + rowB + c0] = v;
      }
      __syncthreads();
    }
  } else {
    // V -> vt[bh][d][n] transposed; two 128-d chunks [128 d][264 n-pad]
    int batch = (int)(rowA >> 11);
    int n_base = (int)(rowA & 2047);
    int dbase = (int)rowB - 2048;
#pragma unroll
    for (int cd = 0; cd < 2; ++cd) {
      if ((wn >> 1) == cd) {
#pragma unroll
        for (int mt = 0; mt < 8; ++mt)
#pragma unroll
          for (int nt = 0; nt < 4; ++nt) {
            int dl = (wn & 1) * 64 + nt * 16 + qr;   // 0..127 within chunk
            int nl = wm * 128 + mt * 16 + quad * 4;  // 0..255
            ushort4 pv;
            pv.x = f2bf(acc[mt][nt][0] + bv[nt]);
            pv.y = f2bf(acc[mt][nt][1] + bv[nt]);
            pv.z = f2bf(acc[mt][nt][2] + bv[nt]);
            pv.w = f2bf(acc[mt][nt][3] + bv[nt]);
            *(ushort4*)&ep[dl * 264 + nl] = pv;
          }
      }
      __syncthreads();
      int dl = tid >> 5;
      int n0 = (tid & 31) * 8;
#pragma unroll
      for (int p = 0; p < 8; ++p) {
        int dd = p * 16 + dl;
        int dglob = dbase + cd * 128 + dd;
        int bh_ = batch * 16 + (dglob >> 6);
        u16x8v v = *(const u16x8v*)&ep[dd * 264 + n0];
        *(u16x8v*)&vtout[(size_t)bh_ * 131072 + (size_t)(dglob & 63) * 2048 + n_base + n0] = v;
      }
      __syncthreads();
    }
  }
}

// ------------- flash attention v6 (round-2 exact, measured-best 56.5us) -------
__global__ void __launch_bounds__(256) attn_kernel(const u16* __restrict__ qkbuf,
                                                   const u16* __restrict__ vt,
                                                   u16* __restrict__ out) {
  __shared__ alignas(16) u16 kbuf[2][128 * 64];
  __shared__ alignas(16) u16 vbuf[2][64 * 128];
  __shared__ alignas(16) u16 pbuf[4][32 * 64];
  int bh = blockIdx.x;
  int b = bh >> 4, h = bh & 15;
  int m0 = blockIdx.y * 128;
  int tid = threadIdx.x;
  int lane = tid & 63, wave = tid >> 6;
  int qr = lane & 15, quad = lane >> 4;

  const u16* kbase = qkbuf + (size_t)(b * SEQ) * 2048 + 1024 + h * 64;
  const u16* vtbase = vt + (size_t)bh * 64 * SEQ;
  u16* pw = &pbuf[wave][0];

  int klr = lane >> 3;
  int kcs = (lane & 7) ^ klr;

  const u16* qbase = qkbuf + (size_t)(b * SEQ + m0 + wave * 32) * 2048 + h * 64;
  bf16x8 qf[2][2];
#pragma unroll
  for (int mt = 0; mt < 2; ++mt)
#pragma unroll
    for (int ks = 0; ks < 2; ++ks)
      qf[mt][ks] = *(const bf16x8*)&qbase[(size_t)(mt * 16 + qr) * 2048 + ks * 32 + quad * 8];

  const bf16x8 vone = __builtin_bit_cast(bf16x8, (u16x8v)((u16)0x3F80));

  f32x4 o[2][4], l5[2];
#pragma unroll
  for (int mt = 0; mt < 2; ++mt) {
    l5[mt] = (f32x4){0.f, 0.f, 0.f, 0.f};
#pragma unroll
    for (int dt = 0; dt < 4; ++dt) o[mt][dt] = (f32x4){0.f, 0.f, 0.f, 0.f};
  }

  auto stage = [&](int buf, int n0) {
#pragma unroll
    for (int i = 0; i < 4; ++i) {
      int kr = wave * 32 + i * 8 + klr;
      ASYNC16(kbase + (size_t)(n0 + kr) * 2048 + kcs * 8,
              &kbuf[buf][(wave * 32 + i * 8) * 64 + lane * 8]);
    }
#pragma unroll
    for (int i = 0; i < 4; ++i) {
      int vr = wave * 16 + i * 4 + (lane >> 4);
      int vcs = ((lane & 7) ^ (vr & 7)) | (lane & 8);
      ASYNC16(vtbase + (size_t)vr * 2048 + n0 + vcs * 8,
              &vbuf[buf][(wave * 16 + i * 4) * 128 + lane * 8]);
    }
  };

  stage(0, 0);

  for (int t = 0; t < 16; ++t) {
    int cur = t & 1;
    __syncthreads();

    if (t + 1 < 16) stage(cur ^ 1, (t + 1) * 128);

#pragma unroll
    for (int sp = 0; sp < 2; ++sp) {
      const u16* kb = &kbuf[cur][sp * 64 * 64];
      const u16* vb = &vbuf[cur][0];

      bf16x8 kf[4][2];
#pragma unroll
      for (int nt = 0; nt < 4; ++nt)
#pragma unroll
        for (int ks = 0; ks < 2; ++ks)
          kf[nt][ks] =
              *(const bf16x8*)&kb[(nt * 16 + qr) * 64 + (((ks * 4 + quad) ^ (qr & 7)) << 3)];

#pragma unroll
      for (int mt = 0; mt < 2; ++mt)
#pragma unroll
        for (int nt = 0; nt < 4; ++nt) {
          f32x4 z = (f32x4){0.f, 0.f, 0.f, 0.f};
          z = MFMA16(kf[nt][0], qf[mt][0], z);
          z = MFMA16(kf[nt][1], qf[mt][1], z);
          float p0 = __builtin_amdgcn_exp2f(z[0]);
          float p1 = __builtin_amdgcn_exp2f(z[1]);
          float p2 = __builtin_amdgcn_exp2f(z[2]);
          float p3 = __builtin_amdgcn_exp2f(z[3]);
          uint2 pk;
          pk.x = cvt2(p0, p1);
          pk.y = cvt2(p2, p3);
          int nb = nt * 16 + quad * 4;
          int addr = (mt * 16 + qr) * 64 + ((((nb >> 3) ^ (qr & 7)) << 3) | (nb & 7));
          *(uint2*)&pw[addr] = pk;
        }

      bf16x8 vf[4][2];
#pragma unroll
      for (int dt = 0; dt < 4; ++dt)
#pragma unroll
        for (int ks = 0; ks < 2; ++ks)
          vf[dt][ks] = *(const bf16x8*)&vb[(dt * 16 + qr) * 128 +
                                           ((sp * 8 + ((ks * 4 + quad) ^ (qr & 7))) << 3)];

      bf16x8 pf[2][2];
#pragma unroll
      for (int mt = 0; mt < 2; ++mt)
#pragma unroll
        for (int ks = 0; ks < 2; ++ks)
          pf[mt][ks] =
              *(const bf16x8*)&pw[(mt * 16 + qr) * 64 + (((ks * 4 + quad) ^ (qr & 7)) << 3)];

#pragma unroll
      for (int mt = 0; mt < 2; ++mt) {
#pragma unroll
        for (int dt = 0; dt < 4; ++dt) {
          o[mt][dt] = MFMA16(pf[mt][0], vf[dt][0], o[mt][dt]);
          o[mt][dt] = MFMA16(pf[mt][1], vf[dt][1], o[mt][dt]);
        }
        l5[mt] = MFMA16(pf[mt][0], vone, l5[mt]);
        l5[mt] = MFMA16(pf[mt][1], vone, l5[mt]);
      }
    }
  }

  u16* obase = out + (size_t)(b * SEQ + m0 + wave * 32) * CH + h * 64;
#pragma unroll
  for (int mt = 0; mt < 2; ++mt)
#pragma unroll
    for (int r = 0; r < 4; ++r) {
      float inv = 1.0f / l5[mt][r];
#pragma unroll
      for (int dt = 0; dt < 4; ++dt)
        obase[(size_t)(mt * 16 + quad * 4 + r) * CH + dt * 16 + qr] = f2bf(o[mt][dt][r] * inv);
    }
}

extern "C" void kernel_launch(void* const* d_in, const int* in_sizes, int n_in,
                              void* d_out, int out_size, void* d_ws, size_t ws_size,
                              hipStream_t stream) {
  const float* x      = (const float*)d_in[0];
  const float* qkv_w  = (const float*)d_in[1];
  const float* qkv_b  = (const float*)d_in[2];
  const float* proj_w = (const float*)d_in[3];
  const float* proj_b = (const float*)d_in[4];
  float* out = (float*)d_out;

  char* w = (char*)d_ws;
  u16* qkqk   = (u16*)w;
  u16* xb     = (u16*)(w + 16777216);
  u16* wprojt = (u16*)(w + 25165824);
  u16* wqkvt  = (u16*)(w + 27262976);
  u16* vt     = (u16*)(w + 33554432);
  u16* attn_bf = xb;

  prep_kernel<<<5120, 256, 0, stream>>>(x, qkv_w, proj_w, xb, wqkvt, wprojt);
  // qkv = x @ qkv_w + b; Q scaled; QK -> qkqk (stride 2048), V -> vt (transposed)
  gemm256_kernel<<<dim3(12, 16), 512, 0, stream>>>(xb, wqkvt, qkv_b, qkqk, vt);
  attn_kernel<<<dim3(32, 16), 256, 0, stream>>>(qkqk, vt, attn_bf);
  // out = attn @ proj_w + b (fp32)
  gemm_kernel<2><<<dim3(8, 64), 256, 0, stream>>>(attn_bf, wprojt, proj_b, nullptr, nullptr, out, 1024, 1);
}

// Round 9
// 177.746 us; speedup vs baseline: 1.0285x; 1.0285x over previous
//
#include <hip/hip_runtime.h>
#include <cstdint>
#include <cstddef>

typedef __bf16 bf16x8 __attribute__((ext_vector_type(8)));
typedef __bf16 bf16x2v __attribute__((ext_vector_type(2)));
typedef unsigned short u16;
typedef u16 u16x8v __attribute__((ext_vector_type(8)));
typedef float  f32x4  __attribute__((ext_vector_type(4)));
typedef unsigned int u32;

#define MFMA16(a, b, c) __builtin_amdgcn_mfma_f32_16x16x32_bf16((a), (b), (c), 0, 0, 0)
#define ASYNC16(g, l)                                                              \
  __builtin_amdgcn_global_load_lds(                                                \
      (const __attribute__((address_space(1))) unsigned int*)(g),                  \
      (__attribute__((address_space(3))) unsigned int*)(l), 16, 0, 0)

__device__ __forceinline__ u16 f2bf(float f) {
  unsigned u = __builtin_bit_cast(unsigned, f);
  u += 0x7fffu + ((u >> 16) & 1u);
  return (u16)(u >> 16);
}

// packed fp32x2 -> bf16x2 (RNE) via hardware cvt
__device__ __forceinline__ u32 cvt2(float a, float b) {
  bf16x2v t;
  t[0] = (__bf16)a;
  t[1] = (__bf16)b;
  return __builtin_bit_cast(u32, t);
}

#define SEQ 2048
#define CH  1024
#define NH  16
#define HD  64
// log2(e) / sqrt(64) folded into stored Q so softmax uses exp2
#define QSCALE 0.18033688011112042f

// ------------- fused prep: cast x + transpose-cast qkv_w + proj_w -------------
// (round-2 original, measured-best)
__global__ void __launch_bounds__(256) prep_kernel(const float* __restrict__ x,
                                                   const float* __restrict__ qkv_w,
                                                   const float* __restrict__ proj_w,
                                                   u16* __restrict__ xb,
                                                   u16* __restrict__ wqkvt,
                                                   u16* __restrict__ wprojt) {
  __shared__ u16 t[64][68];
  int bx = blockIdx.x;
  int tx = threadIdx.x;
  if (bx < 4096) {
    int i = bx * 256 + tx;
    float4 v = ((const float4*)x)[i];
    ushort4 o;
    o.x = f2bf(v.x); o.y = f2bf(v.y); o.z = f2bf(v.z); o.w = f2bf(v.w);
    ((ushort4*)xb)[i] = o;
    return;
  }
  const float* in; u16* out; int R, C, c0, r0;
  if (bx < 4096 + 768) {
    int i = bx - 4096;
    in = qkv_w; out = wqkvt; R = 1024; C = 3072;
    c0 = (i % 48) * 64; r0 = (i / 48) * 64;
  } else {
    int i = bx - 4864;
    in = proj_w; out = wprojt; R = 1024; C = 1024;
    c0 = (i % 16) * 64; r0 = (i / 16) * 64;
  }
  int rr = tx >> 6, cc = tx & 63;
#pragma unroll
  for (int i = 0; i < 16; ++i) {
    int r = i * 4 + rr;
    t[r][cc] = f2bf(in[(size_t)(r0 + r) * C + c0 + cc]);
  }
  __syncthreads();
#pragma unroll
  for (int i = 0; i < 16; ++i) {
    int r = i * 4 + rr;
    out[(size_t)(c0 + r) * R + r0 + cc] = t[cc][r];
  }
}

// ------------- GEMM v4 (round-2, measured-best): BK=64, XOR-swizzled LDS,
//               double-buffered staging, two barriers/iter, coalesced epilogue ----
// Session lessons: XCD swizzle regresses (r3); single-barrier ~+3us (r4);
// 256²/8-phase neutral (r8). This structure is closed.
template <int MT>
__global__ void __launch_bounds__(256) gemm_kernel(const u16* __restrict__ A,
                                                   const u16* __restrict__ Bt,
                                                   const float* __restrict__ bias,
                                                   u16* __restrict__ qk,
                                                   u16* __restrict__ vtout,
                                                   float* __restrict__ outf,
                                                   int K, int mode) {
  constexpr int R = MT * 32;
  __shared__ alignas(16) u16 smem[2 * R * 64 + 2 * 128 * 64];
  auto As = (u16(*)[R * 64])smem;
  auto Bs = (u16(*)[128 * 64])(smem + 2 * R * 64);
  int tid = threadIdx.x;
  int lane = tid & 63, wave = tid >> 6;
  int wm = wave >> 1, wn = wave & 1;
  int qr = lane & 15, quad = lane >> 4;
  size_t rowA = (size_t)blockIdx.y * R;
  size_t rowB = (size_t)blockIdx.x * 128;

  int klr = lane >> 3;
  int kcs = (lane & 7) ^ klr;

  f32x4 acc[MT][4];
#pragma unroll
  for (int mt = 0; mt < MT; ++mt)
#pragma unroll
    for (int nt = 0; nt < 4; ++nt) acc[mt][nt] = (f32x4){0.f, 0.f, 0.f, 0.f};

  auto stage = [&](int buf, int k0) {
#pragma unroll
    for (int i = 0; i < R / 32; ++i) {
      int ar = wave * (R / 4) + i * 8;
      ASYNC16(A + (rowA + ar + klr) * K + k0 + kcs * 8, &As[buf][ar * 64 + lane * 8]);
    }
#pragma unroll
    for (int i = 0; i < 4; ++i) {
      int br = wave * 32 + i * 8;
      ASYNC16(Bt + (rowB + br + klr) * K + k0 + kcs * 8, &Bs[buf][br * 64 + lane * 8]);
    }
  };

  stage(0, 0);
  int iters = K >> 6;
  for (int t = 0; t < iters; ++t) {
    int cur = t & 1;
    __syncthreads();
    if (t + 1 < iters) stage(cur ^ 1, (t + 1) * 64);
#pragma unroll
    for (int ks = 0; ks < 2; ++ks) {
      bf16x8 af[MT], bfr[4];
#pragma unroll
      for (int mt = 0; mt < MT; ++mt) {
        int row = wm * (MT * 16) + mt * 16 + qr;
        af[mt] = *(const bf16x8*)&As[cur][row * 64 + (((ks * 4 + quad) ^ (qr & 7)) << 3)];
      }
#pragma unroll
      for (int nt = 0; nt < 4; ++nt) {
        int row = wn * 64 + nt * 16 + qr;
        bfr[nt] = *(const bf16x8*)&Bs[cur][row * 64 + (((ks * 4 + quad) ^ (qr & 7)) << 3)];
      }
#pragma unroll
      for (int mt = 0; mt < MT; ++mt)
#pragma unroll
        for (int nt = 0; nt < 4; ++nt)
          acc[mt][nt] = MFMA16(af[mt], bfr[nt], acc[mt][nt]);
    }
    __syncthreads();
  }

  __syncthreads();

  if (mode == 1) {
    float* epf = (float*)smem;
#pragma unroll
    for (int nt = 0; nt < 4; ++nt) {
      int cl = wn * 64 + nt * 16 + qr;
      float bv = bias[rowB + cl];
#pragma unroll
      for (int mt = 0; mt < MT; ++mt) {
        int rl = wm * (MT * 16) + mt * 16 + quad * 4;
#pragma unroll
        for (int r = 0; r < 4; ++r)
          epf[(rl + r) * 132 + cl] = acc[mt][nt][r] + bv;
      }
    }
    __syncthreads();
    int rr = wave * 2 + (lane >> 5);
    int cc = (lane & 31) * 4;
#pragma unroll
    for (int p = 0; p < R / 8; ++p) {
      int row = p * 8 + rr;
      float4 v = *(const float4*)&epf[row * 132 + cc];
      *(float4*)&outf[(rowA + row) * 1024 + rowB + cc] = v;
    }
  } else if ((int)rowB < 2048) {
    float sc = ((int)rowB < 1024) ? QSCALE : 1.0f;
    u16* ep = smem;
#pragma unroll
    for (int nt = 0; nt < 4; ++nt) {
      int cl = wn * 64 + nt * 16 + qr;
      float bv = bias[rowB + cl];
#pragma unroll
      for (int mt = 0; mt < MT; ++mt) {
        int rl = wm * (MT * 16) + mt * 16 + quad * 4;
#pragma unroll
        for (int r = 0; r < 4; ++r)
          ep[(rl + r) * 136 + cl] = f2bf((acc[mt][nt][r] + bv) * sc);
      }
    }
    __syncthreads();
    int rr = wave * 4 + (lane >> 4);
    int cc = (lane & 15) * 8;
#pragma unroll
    for (int p = 0; p < R / 16; ++p) {
      int row = p * 16 + rr;
      u16x8v v = *(const u16x8v*)&ep[row * 136 + cc];
      *(u16x8v*)&qk[(rowA + row) * 2048 + rowB + cc] = v;
    }
  } else {
    u16* ep = smem;
#pragma unroll
    for (int nt = 0; nt < 4; ++nt) {
      int cl = wn * 64 + nt * 16 + qr;
      float bv = bias[rowB + cl];
#pragma unroll
      for (int mt = 0; mt < MT; ++mt) {
        int rl = wm * (MT * 16) + mt * 16 + quad * 4;
        ushort4 pv;
        pv.x = f2bf(acc[mt][nt][0] + bv);
        pv.y = f2bf(acc[mt][nt][1] + bv);
        pv.z = f2bf(acc[mt][nt][2] + bv);
        pv.w = f2bf(acc[mt][nt][3] + bv);
        *(ushort4*)&ep[cl * 136 + rl] = pv;
      }
    }
    __syncthreads();
    int batch = (int)(rowA >> 11);
    int n_base = (int)(rowA & 2047);
    int rr = wave * 4 + (lane >> 4);
    int cc = (lane & 15) * 8;
#pragma unroll
    for (int p = 0; p < 8; ++p) {
      int d = p * 16 + rr;
      int cglob = (int)rowB - 2048 + d;
      int bh_ = batch * 16 + (cglob >> 6);
      u16x8v v = *(const u16x8v*)&ep[d * 136 + cc];
      *(u16x8v*)&vtout[(size_t)bh_ * 131072 + (size_t)(cglob & 63) * 2048 + n_base + cc] = v;
    }
  }
}

// ------------- flash attention v10: SAME tile/barriers/LDS/DMA as round-2,
//               but 8 waves x 16 q-rows instead of 4 waves x 32 -------------
// Single-variable TLP test: round-1 confounded tile-shrink with wave count.
// Here the 128x128 tile, 16-barrier cadence, K/V DMA totals, and LDS layout
// are bit-compatible with the measured-best round-2 kernel; only the work
// partition changes: 512 threads, each wave owns 16 query rows (mt dim gone),
// per-wave chains halve, waves/SIMD 2 -> 4. Per-wave state halves (qf 2, o 4)
// so VGPR fits the 128 cap for 4 waves/SIMD (launch_bounds(512,4)).
__global__ void __launch_bounds__(512, 4) attn_kernel(const u16* __restrict__ qkbuf,
                                                      const u16* __restrict__ vt,
                                                      u16* __restrict__ out) {
  __shared__ alignas(16) u16 kbuf[2][128 * 64];
  __shared__ alignas(16) u16 vbuf[2][64 * 128];
  __shared__ alignas(16) u16 pbuf[8][16 * 64];
  int bh = blockIdx.x;
  int b = bh >> 4, h = bh & 15;
  int m0 = blockIdx.y * 128;
  int tid = threadIdx.x;
  int lane = tid & 63, wave = tid >> 6;  // 8 waves
  int qr = lane & 15, quad = lane >> 4;

  const u16* kbase = qkbuf + (size_t)(b * SEQ) * 2048 + 1024 + h * 64;  // K rows, stride 2048
  const u16* vtbase = vt + (size_t)bh * 64 * SEQ;                       // Vt rows, stride 2048
  u16* pw = &pbuf[wave][0];

  int klr = lane >> 3;
  int kcs = (lane & 7) ^ klr;

  // ---- Q fragments (16 rows per wave) ----
  const u16* qbase = qkbuf + (size_t)(b * SEQ + m0 + wave * 16) * 2048 + h * 64;
  bf16x8 qf[2];
#pragma unroll
  for (int ks = 0; ks < 2; ++ks)
    qf[ks] = *(const bf16x8*)&qbase[(size_t)qr * 2048 + ks * 32 + quad * 8];

  const bf16x8 vone = __builtin_bit_cast(bf16x8, (u16x8v)((u16)0x3F80));

  f32x4 o[4], l5;
  l5 = (f32x4){0.f, 0.f, 0.f, 0.f};
#pragma unroll
  for (int dt = 0; dt < 4; ++dt) o[dt] = (f32x4){0.f, 0.f, 0.f, 0.f};

  // 8 waves split the same DMA: K 128 rows -> 16/wave (2 chunks of 8);
  // V 64 rows -> 8/wave (2 chunks of 4). Same addresses/swizzle as round-2.
  auto stage = [&](int buf, int n0) {
#pragma unroll
    for (int i = 0; i < 2; ++i) {
      int kr = wave * 16 + i * 8 + klr;
      ASYNC16(kbase + (size_t)(n0 + kr) * 2048 + kcs * 8,
              &kbuf[buf][(wave * 16 + i * 8) * 64 + lane * 8]);
    }
#pragma unroll
    for (int i = 0; i < 2; ++i) {
      int vr = wave * 8 + i * 4 + (lane >> 4);
      int vcs = ((lane & 7) ^ (vr & 7)) | (lane & 8);
      ASYNC16(vtbase + (size_t)vr * 2048 + n0 + vcs * 8,
              &vbuf[buf][(wave * 8 + i * 4) * 128 + lane * 8]);
    }
  };

  stage(0, 0);

  for (int t = 0; t < 16; ++t) {
    int cur = t & 1;
    __syncthreads();  // own DMA into buf[cur] drained; buf[cur^1] reads finished

    if (t + 1 < 16) stage(cur ^ 1, (t + 1) * 128);

#pragma unroll
    for (int sp = 0; sp < 2; ++sp) {
      const u16* kb = &kbuf[cur][sp * 64 * 64];
      const u16* vb = &vbuf[cur][0];

      bf16x8 kf[4][2];
#pragma unroll
      for (int nt = 0; nt < 4; ++nt)
#pragma unroll
        for (int ks = 0; ks < 2; ++ks)
          kf[nt][ks] =
              *(const bf16x8*)&kb[(nt * 16 + qr) * 64 + (((ks * 4 + quad) ^ (qr & 7)) << 3)];

#pragma unroll
      for (int nt = 0; nt < 4; ++nt) {
        f32x4 z = (f32x4){0.f, 0.f, 0.f, 0.f};
        z = MFMA16(kf[nt][0], qf[0], z);
        z = MFMA16(kf[nt][1], qf[1], z);
        float p0 = __builtin_amdgcn_exp2f(z[0]);
        float p1 = __builtin_amdgcn_exp2f(z[1]);
        float p2 = __builtin_amdgcn_exp2f(z[2]);
        float p3 = __builtin_amdgcn_exp2f(z[3]);
        uint2 pk;
        pk.x = cvt2(p0, p1);
        pk.y = cvt2(p2, p3);
        int nb = nt * 16 + quad * 4;
        int addr = qr * 64 + ((((nb >> 3) ^ (qr & 7)) << 3) | (nb & 7));
        *(uint2*)&pw[addr] = pk;
      }

      bf16x8 vf[4][2];
#pragma unroll
      for (int dt = 0; dt < 4; ++dt)
#pragma unroll
        for (int ks = 0; ks < 2; ++ks)
          vf[dt][ks] = *(const bf16x8*)&vb[(dt * 16 + qr) * 128 +
                                           ((sp * 8 + ((ks * 4 + quad) ^ (qr & 7))) << 3)];

      bf16x8 pf[2];
#pragma unroll
      for (int ks = 0; ks < 2; ++ks)
        pf[ks] = *(const bf16x8*)&pw[qr * 64 + (((ks * 4 + quad) ^ (qr & 7)) << 3)];

#pragma unroll
      for (int dt = 0; dt < 4; ++dt) {
        o[dt] = MFMA16(pf[0], vf[dt][0], o[dt]);
        o[dt] = MFMA16(pf[1], vf[dt][1], o[dt]);
      }
      l5 = MFMA16(pf[0], vone, l5);
      l5 = MFMA16(pf[1], vone, l5);
    }
  }

  u16* obase = out + (size_t)(b * SEQ + m0 + wave * 16) * CH + h * 64;
#pragma unroll
  for (int r = 0; r < 4; ++r) {
    float inv = 1.0f / l5[r];
#pragma unroll
    for (int dt = 0; dt < 4; ++dt)
      obase[(size_t)(quad * 4 + r) * CH + dt * 16 + qr] = f2bf(o[dt][r] * inv);
  }
}

extern "C" void kernel_launch(void* const* d_in, const int* in_sizes, int n_in,
                              void* d_out, int out_size, void* d_ws, size_t ws_size,
                              hipStream_t stream) {
  const float* x      = (const float*)d_in[0];
  const float* qkv_w  = (const float*)d_in[1];
  const float* qkv_b  = (const float*)d_in[2];
  const float* proj_w = (const float*)d_in[3];
  const float* proj_b = (const float*)d_in[4];
  float* out = (float*)d_out;

  char* w = (char*)d_ws;
  // ws layout (42 MB):
  //   qkqk  : 4096x2048 bf16 (Q scaled | K, stride 2048) = 16777216 B
  //   xb    : 4096x1024 bf16 = 8388608 B (reused as attn_bf after gemm1)
  //   wprojt: 1024x1024 bf16 = 2097152 B
  //   wqkvt : 3072x1024 bf16 = 6291456 B
  //   vt    : (B*H)x64x2048 bf16 = 8388608 B (written directly by gemm1 epilogue)
  u16* qkqk   = (u16*)w;
  u16* xb     = (u16*)(w + 16777216);
  u16* wprojt = (u16*)(w + 25165824);
  u16* wqkvt  = (u16*)(w + 27262976);
  u16* vt     = (u16*)(w + 33554432);
  u16* attn_bf = xb;

  prep_kernel<<<5120, 256, 0, stream>>>(x, qkv_w, proj_w, xb, wqkvt, wprojt);
  // qkv = x @ qkv_w + b; Q scaled; QK -> qkqk (stride 2048), V -> vt (transposed)
  gemm_kernel<4><<<dim3(24, 32), 256, 0, stream>>>(xb, wqkvt, qkv_b, qkqk, vt, nullptr, 1024, 0);
  attn_kernel<<<dim3(32, 16), 512, 0, stream>>>(qkqk, vt, attn_bf);
  // out = attn @ proj_w + b (fp32)
  gemm_kernel<2><<<dim3(8, 64), 256, 0, stream>>>(attn_bf, wprojt, proj_b, nullptr, nullptr, out, 1024, 1);
}